// Round 3
// baseline (1352.760 us; speedup 1.0000x reference)
//
#include <hip/hip_runtime.h>
#include <hip/hip_bf16.h>

#define N_NODES 30000
#define N_EDGES 480000
#define NFEAT 92
#define EFEAT 50
#define PADK 52   // EFEAT padded to 16B multiple (52*4=208)
#define D1 64
#define ZD 178
#define NL 3
#define NG 256
#define BN_EPS 1e-5f

// ---------------- lin0: h = relu(x @ W0 + b0) ----------------
extern "C" __global__ void __launch_bounds__(256)
k_lin0(const float* __restrict__ x, const float* __restrict__ w,
       const float* __restrict__ b, float* __restrict__ h) {
  const int lane = threadIdx.x & 63;
  const int wave = (blockIdx.x * blockDim.x + threadIdx.x) >> 6;
  const int nw = (gridDim.x * blockDim.x) >> 6;
  float wreg[NFEAT];
#pragma unroll
  for (int k = 0; k < NFEAT; ++k) wreg[k] = w[k * D1 + lane];
  const float bj = b[lane];
  for (int i = wave; i < N_NODES; i += nw) {
    const float2* xr = (const float2*)(x + (size_t)i * NFEAT);
    float acc = bj;
#pragma unroll
    for (int k = 0; k < NFEAT / 2; ++k) {
      const float2 v = xr[k];
      acc = fmaf(v.x, wreg[2 * k], acc);
      acc = fmaf(v.y, wreg[2 * k + 1], acc);
    }
    h[(size_t)i * D1 + lane] = fmaxf(acc, 0.0f);
  }
}

// ---------------- CSR build ----------------
extern "C" __global__ void __launch_bounds__(256)
k_cnt(const int* __restrict__ ei, int* __restrict__ cnt) {
  const int e = blockIdx.x * blockDim.x + threadIdx.x;
  if (e < N_EDGES) atomicAdd(&cnt[ei[N_EDGES + e]], 1);
}

extern "C" __global__ void __launch_bounds__(1024)
k_scan(const int* __restrict__ cnt, int* __restrict__ rp, int* __restrict__ wptr) {
  const int t = threadIdx.x;
  const int CH = (N_NODES + 1023) / 1024;  // 30
  int vals[CH];
  int s = 0;
#pragma unroll
  for (int k = 0; k < CH; ++k) {
    const int idx = t * CH + k;
    const int c = (idx < N_NODES) ? cnt[idx] : 0;
    vals[k] = s;
    s += c;
  }
  __shared__ int bs[1024];
  bs[t] = s;
  __syncthreads();
  for (int off = 1; off < 1024; off <<= 1) {
    int v = 0;
    if (t >= off) v = bs[t - off];
    __syncthreads();
    if (t >= off) bs[t] += v;
    __syncthreads();
  }
  const int prefix = (t == 0) ? 0 : bs[t - 1];
#pragma unroll
  for (int k = 0; k < CH; ++k) {
    const int idx = t * CH + k;
    if (idx < N_NODES) {
      rp[idx] = prefix + vals[k];
      wptr[idx] = prefix + vals[k];
    }
  }
  if (t == 1023) rp[N_NODES] = bs[1023];
}

extern "C" __global__ void __launch_bounds__(256)
k_scatter(const int* __restrict__ ei, int* __restrict__ wptr,
          int* __restrict__ srcs, int* __restrict__ eidx) {
  const int e = blockIdx.x * blockDim.x + threadIdx.x;
  if (e < N_EDGES) {
    const int d = ei[N_EDGES + e];
    const int pos = atomicAdd(&wptr[d], 1);
    srcs[pos] = ei[e];
    eidx[pos] = e;
  }
}

// ---------------- permute edge_attr into CSR order ----------------
extern "C" __global__ void __launch_bounds__(256)
k_perm(const float* __restrict__ ea, const int* __restrict__ eidx,
       float* __restrict__ eap) {
  const int lane = threadIdx.x & 63;
  const int wave = (blockIdx.x * blockDim.x + threadIdx.x) >> 6;
  const int nw = (gridDim.x * blockDim.x) >> 6;
  for (int pos = wave; pos < N_EDGES; pos += nw) {
    const int e = __builtin_amdgcn_readfirstlane(eidx[pos]);
    if (lane < EFEAT)
      eap[(size_t)pos * EFEAT + lane] = ea[(size_t)e * EFEAT + lane];
  }
}

// ---------------- weight transpose: wT[(l*2+m)][j][k], row stride PADK ------
extern "C" __global__ void __launch_bounds__(256)
k_wprep(const float* __restrict__ conv_wf, const float* __restrict__ conv_ws,
        float* __restrict__ wT) {
  const int idx = blockIdx.x * blockDim.x + threadIdx.x;
  const int total = NL * 2 * D1 * PADK;
  if (idx >= total) return;
  const int k = idx % PADK;
  const int j = (idx / PADK) % D1;
  const int m = (idx / (PADK * D1)) % 2;
  const int l = idx / (PADK * D1 * 2);
  float v = 0.0f;
  if (k < EFEAT) {
    const float* W = (m == 0) ? conv_wf : conv_ws;
    v = W[(size_t)l * ZD * D1 + (size_t)(128 + k) * D1 + j];
  }
  wT[idx] = v;
}

// ---------------- node projections ----------------
extern "C" __global__ void __launch_bounds__(256)
k_nodeproj(const float* __restrict__ h, const float* __restrict__ wf,
           const float* __restrict__ wsm, float* __restrict__ pf,
           float* __restrict__ ps) {
  const int lane = threadIdx.x & 63;
  const int w = threadIdx.x >> 6;  // 0..3
  const float* W = (w < 2) ? wf : wsm;
  const int roff = (w & 1) * 64;
  float wreg[D1];
#pragma unroll
  for (int k = 0; k < D1; ++k) wreg[k] = W[(size_t)(roff + k) * D1 + lane];
  float* out = (w < 2) ? pf : ps;
  const int ooff = (w & 1) * 64;
  for (int i = blockIdx.x; i < N_NODES; i += gridDim.x) {
    const float4* hr = (const float4*)(h + (size_t)i * D1);
    float acc = 0.0f;
#pragma unroll
    for (int k4 = 0; k4 < D1 / 4; ++k4) {
      const float4 v = hr[k4];
      acc = fmaf(v.x, wreg[4 * k4 + 0], acc);
      acc = fmaf(v.y, wreg[4 * k4 + 1], acc);
      acc = fmaf(v.z, wreg[4 * k4 + 2], acc);
      acc = fmaf(v.w, wreg[4 * k4 + 3], acc);
    }
    out[(size_t)i * 128 + ooff + lane] = acc;
  }
}

// ---------------- CSR edge kernel: wave per dst node; fused BN stats --------
extern "C" __global__ void __launch_bounds__(256, 2)
k_edge2(const float* __restrict__ pf, const float* __restrict__ ps,
        const float* __restrict__ eap, const int* __restrict__ srcs,
        const int* __restrict__ eidx,  // null => eap already CSR-ordered
        const int* __restrict__ rp,
        const float* __restrict__ wfT, const float* __restrict__ wsT,
        const float* __restrict__ bfp, const float* __restrict__ bsp,
        float* __restrict__ aggr, float* __restrict__ musum,
        float* __restrict__ sqsum) {
  const int lane = threadIdx.x & 63;
  // per-lane contiguous weight rows -> dwordx4 loads -> VGPR-resident quads
  const float4* rf4 = (const float4*)(wfT + (size_t)lane * PADK);
  const float4* rs4 = (const float4*)(wsT + (size_t)lane * PADK);
  float4 wfv[12], wsv[12];
#pragma unroll
  for (int q = 0; q < 12; ++q) {
    wfv[q] = rf4[q];
    wsv[q] = rs4[q];
  }
  const float2 wft = ((const float2*)rf4)[24];
  const float2 wst = ((const float2*)rs4)[24];
  const float bfj = bfp[lane], bsj = bsp[lane];
  const int wid = __builtin_amdgcn_readfirstlane(blockIdx.x * 4 + (threadIdx.x >> 6));
  const int nw = gridDim.x * 4;
  float ssum = 0.0f, ssq = 0.0f;
  for (int i = wid; i < N_NODES; i += nw) {
    const int start = __builtin_amdgcn_readfirstlane(rp[i]);
    const int end = __builtin_amdgcn_readfirstlane(rp[i + 1]);
    const float pfd = pf[(size_t)i * 128 + lane] + bfj;
    const float psd = ps[(size_t)i * 128 + lane] + bsj;
    float acc = 0.0f;
    for (int e = start; e < end; ++e) {
      const int s = __builtin_amdgcn_readfirstlane(srcs[e]);
      const int ee = eidx ? __builtin_amdgcn_readfirstlane(eidx[e]) : e;
      float af = pfd + pf[(size_t)s * 128 + 64 + lane];
      float as = psd + ps[(size_t)s * 128 + 64 + lane];
      const float2* row = (const float2*)(eap + (size_t)ee * EFEAT);
#pragma unroll
      for (int q = 0; q < 12; ++q) {
        const float2 a = row[2 * q];
        const float2 b = row[2 * q + 1];
        af = fmaf(a.x, wfv[q].x, af);
        af = fmaf(a.y, wfv[q].y, af);
        af = fmaf(b.x, wfv[q].z, af);
        af = fmaf(b.y, wfv[q].w, af);
        as = fmaf(a.x, wsv[q].x, as);
        as = fmaf(a.y, wsv[q].y, as);
        as = fmaf(b.x, wsv[q].z, as);
        as = fmaf(b.y, wsv[q].w, as);
      }
      const float2 t = row[24];
      af = fmaf(t.x, wft.x, af);
      af = fmaf(t.y, wft.y, af);
      as = fmaf(t.x, wst.x, as);
      as = fmaf(t.y, wst.y, as);
      const float sg = __builtin_amdgcn_rcpf(1.0f + __expf(-af));
      const float sp = __logf(1.0f + __expf(as));
      acc += sg * sp;
    }
    const float inv = 1.0f / fmaxf((float)(end - start), 1.0f);
    const float m = acc * inv;
    aggr[(size_t)i * D1 + lane] = m;
    ssum += m;
    ssq = fmaf(m, m, ssq);
  }
  atomicAdd(&musum[lane], ssum);
  atomicAdd(&sqsum[lane], ssq);
}

// ---------------- h = relu(h + bn(aggr)) with inline BN finalize ------------
extern "C" __global__ void __launch_bounds__(256)
k_update(float* __restrict__ h, const float* __restrict__ aggr,
         const float* __restrict__ musum, const float* __restrict__ sqsum,
         const float* __restrict__ gamma, const float* __restrict__ beta) {
  const size_t idx = (size_t)blockIdx.x * blockDim.x + threadIdx.x;
  if (idx >= (size_t)N_NODES * D1) return;
  const int j = (int)(idx & 63);
  const float mu = musum[j] * (1.0f / N_NODES);
  const float var = sqsum[j] * (1.0f / N_NODES) - mu * mu;
  const float r = gamma[j] * rsqrtf(var + BN_EPS);
  const float sh = beta[j] - mu * r;
  h[idx] = fmaxf(h[idx] + fmaf(aggr[idx], r, sh), 0.0f);
}

// ---------------- global mean pool (atomic) ----------------
extern "C" __global__ void __launch_bounds__(256)
k_pool(const float* __restrict__ h, const int* __restrict__ batch,
       float* __restrict__ pooled, float* __restrict__ gcnt) {
  const int lane = threadIdx.x & 63;
  const int wave = (blockIdx.x * blockDim.x + threadIdx.x) >> 6;
  const int nw = (gridDim.x * blockDim.x) >> 6;
  for (int i = wave; i < N_NODES; i += nw) {
    const int b = batch[i];
    atomicAdd(&pooled[(size_t)b * D1 + lane], h[(size_t)i * D1 + lane]);
    if (lane == 0) atomicAdd(&gcnt[b], 1.0f);
  }
}

// ---------------- final MLP chain, one wave per graph ----------------
extern "C" __global__ void __launch_bounds__(64)
k_mlp(const float* __restrict__ pooled, const float* __restrict__ gcnt,
      const float* __restrict__ lin1_w, const float* __restrict__ lin1_b,
      const float* __restrict__ fc_w, const float* __restrict__ fc_b,
      const float* __restrict__ lin2_w, const float* __restrict__ lin2_b,
      float* __restrict__ out) {
  const int g = blockIdx.x;
  const int j = threadIdx.x;
  __shared__ float vin[D1];
  const float inv = 1.0f / fmaxf(gcnt[g], 1.0f);
  float v = pooled[(size_t)g * D1 + j] * inv;
  for (int layer = 0; layer < 3; ++layer) {
    vin[j] = v;
    __syncthreads();
    const float* W;
    const float* B;
    if (layer == 0) {
      W = lin1_w;
      B = lin1_b;
    } else {
      W = fc_w + (size_t)(layer - 1) * D1 * D1;
      B = fc_b + (size_t)(layer - 1) * D1;
    }
    float acc = B[j];
#pragma unroll 16
    for (int k = 0; k < D1; ++k) acc = fmaf(vin[k], W[k * D1 + j], acc);
    v = fmaxf(acc, 0.0f);
    __syncthreads();
  }
  float p = v * lin2_w[j];
#pragma unroll
  for (int off = 32; off > 0; off >>= 1) p += __shfl_down(p, off);
  if (j == 0) out[g] = p + lin2_b[0];
}

extern "C" void kernel_launch(void* const* d_in, const int* in_sizes, int n_in,
                              void* d_out, int out_size, void* d_ws, size_t ws_size,
                              hipStream_t stream) {
  const float* x        = (const float*)d_in[0];
  const float* ea       = (const float*)d_in[1];
  const float* lin0_w   = (const float*)d_in[2];
  const float* lin0_b   = (const float*)d_in[3];
  const float* conv_wf  = (const float*)d_in[4];
  const float* conv_bf  = (const float*)d_in[5];
  const float* conv_ws  = (const float*)d_in[6];
  const float* conv_bs  = (const float*)d_in[7];
  const float* bn_gamma = (const float*)d_in[8];
  const float* bn_beta  = (const float*)d_in[9];
  const float* lin1_w   = (const float*)d_in[10];
  const float* lin1_b   = (const float*)d_in[11];
  const float* fc_w     = (const float*)d_in[12];
  const float* fc_b     = (const float*)d_in[13];
  const float* lin2_w   = (const float*)d_in[14];
  const float* lin2_b   = (const float*)d_in[15];
  const int*   ei       = (const int*)d_in[16];
  const int*   batch    = (const int*)d_in[17];

  float* wsp = (float*)d_ws;
  float* h      = wsp;                          // N*64
  float* pf     = h + (size_t)N_NODES * 64;     // N*128
  float* ps     = pf + (size_t)N_NODES * 128;   // N*128
  float* aggr   = ps + (size_t)N_NODES * 128;   // N*64
  float* musum  = aggr + (size_t)N_NODES * 64;  // 64
  float* sqsum  = musum + 64;                   // 64
  float* pooled = sqsum + 64;                   // G*64
  float* gcnt   = pooled + (size_t)NG * 64;     // G
  float* wT     = gcnt + NG;                    // 3*2*64*PADK
  int*   cnt    = (int*)(wT + (size_t)NL * 2 * D1 * PADK);  // N
  int*   rp     = cnt + N_NODES;                // N+1
  int*   wptr   = rp + N_NODES + 1;             // N
  int*   srcs   = wptr + N_NODES;               // E
  int*   eidx   = srcs + N_EDGES;               // E
  float* eap    = (float*)(eidx + N_EDGES);     // E*50 (optional)

  const size_t need_bytes =
      ((char*)(eap + (size_t)N_EDGES * EFEAT)) - (char*)d_ws;
  const bool use_perm = ws_size >= need_bytes;

  hipMemsetAsync(cnt, 0, N_NODES * sizeof(int), stream);
  hipMemsetAsync(pooled, 0, (NG * D1 + NG) * sizeof(float), stream);

  k_lin0<<<256, 256, 0, stream>>>(x, lin0_w, lin0_b, h);
  k_cnt<<<(N_EDGES + 255) / 256, 256, 0, stream>>>(ei, cnt);
  k_scan<<<1, 1024, 0, stream>>>(cnt, rp, wptr);
  k_scatter<<<(N_EDGES + 255) / 256, 256, 0, stream>>>(ei, wptr, srcs, eidx);
  k_wprep<<<(NL * 2 * D1 * PADK + 255) / 256, 256, 0, stream>>>(conv_wf, conv_ws, wT);
  if (use_perm) k_perm<<<2048, 256, 0, stream>>>(ea, eidx, eap);

  const float* ea_use = use_perm ? eap : ea;
  const int* eidx_use = use_perm ? nullptr : eidx;

  for (int l = 0; l < NL; ++l) {
    const float* wfl = conv_wf + (size_t)l * ZD * D1;
    const float* wsl = conv_ws + (size_t)l * ZD * D1;
    k_nodeproj<<<512, 256, 0, stream>>>(h, wfl, wsl, pf, ps);
    hipMemsetAsync(musum, 0, 128 * sizeof(float), stream);
    k_edge2<<<1875, 256, 0, stream>>>(pf, ps, ea_use, srcs, eidx_use, rp,
                                      wT + (size_t)(l * 2 + 0) * D1 * PADK,
                                      wT + (size_t)(l * 2 + 1) * D1 * PADK,
                                      conv_bf + (size_t)l * D1,
                                      conv_bs + (size_t)l * D1,
                                      aggr, musum, sqsum);
    k_update<<<(N_NODES * D1 + 255) / 256, 256, 0, stream>>>(
        h, aggr, musum, sqsum, bn_gamma + (size_t)l * D1, bn_beta + (size_t)l * D1);
  }

  k_pool<<<128, 256, 0, stream>>>(h, batch, pooled, gcnt);
  k_mlp<<<NG, 64, 0, stream>>>(pooled, gcnt, lin1_w, lin1_b, fc_w, fc_b,
                               lin2_w, lin2_b, (float*)d_out);
}

// Round 4
// 967.989 us; speedup vs baseline: 1.3975x; 1.3975x over previous
//
#include <hip/hip_runtime.h>
#include <hip/hip_bf16.h>

#define N_NODES 30000
#define N_EDGES 480000
#define NFEAT 92
#define EFEAT 50
#define D1 64
#define ZD 178
#define NL 3
#define NG 256
#define BN_EPS 1e-5f
#define NTILES (N_EDGES / 16)   // 30000
#define EDGE_BLOCKS 1875        // 7500 waves x 4 tiles = 30000 exactly

typedef __attribute__((ext_vector_type(8))) short bf16x8;
typedef __attribute__((ext_vector_type(4))) float f32x4;

static __device__ __forceinline__ unsigned short f2bf(float v) {
  __hip_bfloat16 b = __float2bfloat16(v);
  return *(unsigned short*)&b;
}

// ---------------- lin0: h = relu(x @ W0 + b0) ----------------
extern "C" __global__ void __launch_bounds__(256)
k_lin0(const float* __restrict__ x, const float* __restrict__ w,
       const float* __restrict__ b, float* __restrict__ h) {
  const int lane = threadIdx.x & 63;
  const int wave = (blockIdx.x * blockDim.x + threadIdx.x) >> 6;
  const int nw = (gridDim.x * blockDim.x) >> 6;
  float wreg[NFEAT];
#pragma unroll
  for (int k = 0; k < NFEAT; ++k) wreg[k] = w[k * D1 + lane];
  const float bj = b[lane];
  for (int i = wave; i < N_NODES; i += nw) {
    const float2* xr = (const float2*)(x + (size_t)i * NFEAT);
    float acc = bj;
#pragma unroll
    for (int k = 0; k < NFEAT / 2; ++k) {
      const float2 v = xr[k];
      acc = fmaf(v.x, wreg[2 * k], acc);
      acc = fmaf(v.y, wreg[2 * k + 1], acc);
    }
    h[(size_t)i * D1 + lane] = fmaxf(acc, 0.0f);
  }
}

// ---------------- CSR build ----------------
extern "C" __global__ void __launch_bounds__(256)
k_cnt(const int* __restrict__ ei, int* __restrict__ cnt) {
  const int e = blockIdx.x * blockDim.x + threadIdx.x;
  if (e < N_EDGES) atomicAdd(&cnt[ei[N_EDGES + e]], 1);
}

extern "C" __global__ void __launch_bounds__(1024)
k_scan(const int* __restrict__ cnt, int* __restrict__ rp, int* __restrict__ wptr) {
  const int t = threadIdx.x;
  const int CH = (N_NODES + 1023) / 1024;  // 30
  int vals[CH];
  int s = 0;
#pragma unroll
  for (int k = 0; k < CH; ++k) {
    const int idx = t * CH + k;
    const int c = (idx < N_NODES) ? cnt[idx] : 0;
    vals[k] = s;
    s += c;
  }
  __shared__ int bs[1024];
  bs[t] = s;
  __syncthreads();
  for (int off = 1; off < 1024; off <<= 1) {
    int v = 0;
    if (t >= off) v = bs[t - off];
    __syncthreads();
    if (t >= off) bs[t] += v;
    __syncthreads();
  }
  const int prefix = (t == 0) ? 0 : bs[t - 1];
#pragma unroll
  for (int k = 0; k < CH; ++k) {
    const int idx = t * CH + k;
    if (idx < N_NODES) {
      rp[idx] = prefix + vals[k];
      wptr[idx] = prefix + vals[k];
    }
  }
  if (t == 1023) rp[N_NODES] = bs[1023];
}

extern "C" __global__ void __launch_bounds__(256)
k_scatter(const int* __restrict__ ei, int* __restrict__ wptr,
          int* __restrict__ srcs, int* __restrict__ dsts,
          int* __restrict__ eidx) {
  const int e = blockIdx.x * blockDim.x + threadIdx.x;
  if (e < N_EDGES) {
    const int d = ei[N_EDGES + e];
    const int pos = atomicAdd(&wptr[d], 1);
    srcs[pos] = ei[e];
    dsts[pos] = d;
    eidx[pos] = e;
  }
}

extern "C" __global__ void __launch_bounds__(256)
k_inv(const int* __restrict__ rp, float* __restrict__ invc) {
  const int i = blockIdx.x * blockDim.x + threadIdx.x;
  if (i < N_NODES) {
    const int c = rp[i + 1] - rp[i];
    invc[i] = 1.0f / fmaxf((float)c, 1.0f);
  }
}

// ---------------- pack edge_attr -> bf16, K padded to 64 (edge order) -------
extern "C" __global__ void __launch_bounds__(256)
k_eapack(const float* __restrict__ ea, unsigned short* __restrict__ eapb) {
  const size_t idx = (size_t)blockIdx.x * blockDim.x + threadIdx.x;
  if (idx >= (size_t)N_EDGES * 64) return;
  const size_t e = idx >> 6;
  const int k = (int)(idx & 63);
  const float v = (k < EFEAT) ? ea[e * EFEAT + k] : 0.0f;
  eapb[idx] = f2bf(v);
}

// ---------------- prep B fragments (bf16) for all layers --------------------
// Bp[l][(m*2+t)*4+n][lane][j] = W2[k=t*32+(lane>>4)*8+j][feat=(lane&15)*4+n]
extern "C" __global__ void __launch_bounds__(256)
k_wprep(const float* __restrict__ conv_wf, const float* __restrict__ conv_ws,
        unsigned short* __restrict__ Bp) {
  const int idx = blockIdx.x * blockDim.x + threadIdx.x;
  const int total = NL * 16 * 64 * 8;
  if (idx >= total) return;
  const int j = idx & 7;
  const int lane = (idx >> 3) & 63;
  const int frag = (idx >> 9) & 15;   // (m*2+t)*4+n
  const int l = idx >> 13;
  const int n = frag & 3;
  const int t = (frag >> 2) & 1;
  const int m = frag >> 3;
  const int k = t * 32 + (lane >> 4) * 8 + j;
  const int feat = (lane & 15) * 4 + n;
  float v = 0.0f;
  if (k < EFEAT) {
    const float* W = (m == 0) ? conv_wf : conv_ws;
    v = W[(size_t)l * ZD * D1 + (size_t)(128 + k) * D1 + feat];
  }
  Bp[idx] = f2bf(v);
}

// ---------------- node projections (fp32) ----------------
extern "C" __global__ void __launch_bounds__(256)
k_nodeproj(const float* __restrict__ h, const float* __restrict__ wf,
           const float* __restrict__ wsm, float* __restrict__ pf,
           float* __restrict__ ps) {
  const int lane = threadIdx.x & 63;
  const int w = threadIdx.x >> 6;  // 0..3
  const float* W = (w < 2) ? wf : wsm;
  const int roff = (w & 1) * 64;
  float wreg[D1];
#pragma unroll
  for (int k = 0; k < D1; ++k) wreg[k] = W[(size_t)(roff + k) * D1 + lane];
  float* out = (w < 2) ? pf : ps;
  const int ooff = (w & 1) * 64;
  for (int i = blockIdx.x; i < N_NODES; i += gridDim.x) {
    const float4* hr = (const float4*)(h + (size_t)i * D1);
    float acc = 0.0f;
#pragma unroll
    for (int k4 = 0; k4 < D1 / 4; ++k4) {
      const float4 v = hr[k4];
      acc = fmaf(v.x, wreg[4 * k4 + 0], acc);
      acc = fmaf(v.y, wreg[4 * k4 + 1], acc);
      acc = fmaf(v.z, wreg[4 * k4 + 2], acc);
      acc = fmaf(v.w, wreg[4 * k4 + 3], acc);
    }
    out[(size_t)i * 128 + ooff + lane] = acc;
  }
}

// ---------------- MFMA edge kernel: one wave per 16-edge CSR tile -----------
// af tile = eapb[rows] @ Wf2 (bf16 MFMA, K=64) + pf_dst + pf_src + bias (fp32 C-init)
// m = sigmoid(af)*softplus(as) -> LDS -> segmented reduce -> atomicAdd mean.
extern "C" __global__ void __launch_bounds__(256, 2)
k_edgemm(const float* __restrict__ pf, const float* __restrict__ ps,
         const unsigned short* __restrict__ eapb,
         const int* __restrict__ srcs, const int* __restrict__ dsts,
         const int* __restrict__ eidx, const float* __restrict__ invc,
         const unsigned short* __restrict__ Bp,
         const float* __restrict__ bfp, const float* __restrict__ bsp,
         float* __restrict__ aggr) {
  const int lane = threadIdx.x & 63;
  const int wv = threadIdx.x >> 6;
  const int col = lane & 15;
  const int quad = lane >> 4;
  __shared__ float mlds[4][16][68];

  bf16x8 Bf[2][2][4];
#pragma unroll
  for (int m = 0; m < 2; ++m)
#pragma unroll
    for (int t = 0; t < 2; ++t)
#pragma unroll
      for (int n = 0; n < 4; ++n)
        Bf[m][t][n] = *(const bf16x8*)(Bp + ((((m * 2 + t) * 4 + n) * 64 + lane) * 8));

  const f32x4 bf4 = *(const f32x4*)(bfp + col * 4);
  const f32x4 bs4 = *(const f32x4*)(bsp + col * 4);

  const int wave0 = blockIdx.x * 4 + wv;
  for (int t = wave0; t < NTILES; t += EDGE_BLOCKS * 4) {
    const int base = t * 16;
    // A fragments (gathered bf16 rows, 16B per lane per ktile)
    const int e_m = eidx[base + col];
    const bf16x8 Af0 = *(const bf16x8*)(eapb + (size_t)e_m * 64 + quad * 8);
    const bf16x8 Af1 = *(const bf16x8*)(eapb + (size_t)e_m * 64 + 32 + quad * 8);

    // C init: fp32 node projections + bias
    f32x4 aF[4], aS[4];
#pragma unroll
    for (int r = 0; r < 4; ++r) {
      const int er = base + quad * 4 + r;
      const int d = dsts[er];
      const int s = srcs[er];
      const f32x4 pfd = *(const f32x4*)(pf + (size_t)d * 128 + col * 4);
      const f32x4 pfs = *(const f32x4*)(pf + (size_t)s * 128 + 64 + col * 4);
      const f32x4 psd = *(const f32x4*)(ps + (size_t)d * 128 + col * 4);
      const f32x4 pss = *(const f32x4*)(ps + (size_t)s * 128 + 64 + col * 4);
#pragma unroll
      for (int n = 0; n < 4; ++n) {
        aF[n][r] = pfd[n] + pfs[n] + bf4[n];
        aS[n][r] = psd[n] + pss[n] + bs4[n];
      }
    }

#pragma unroll
    for (int n = 0; n < 4; ++n) {
      aF[n] = __builtin_amdgcn_mfma_f32_16x16x32_bf16(Af0, Bf[0][0][n], aF[n], 0, 0, 0);
      aF[n] = __builtin_amdgcn_mfma_f32_16x16x32_bf16(Af1, Bf[0][1][n], aF[n], 0, 0, 0);
      aS[n] = __builtin_amdgcn_mfma_f32_16x16x32_bf16(Af0, Bf[1][0][n], aS[n], 0, 0, 0);
      aS[n] = __builtin_amdgcn_mfma_f32_16x16x32_bf16(Af1, Bf[1][1][n], aS[n], 0, 0, 0);
    }

    // epilogue: m = sigmoid(af) * softplus(as); stage into LDS tile
#pragma unroll
    for (int r = 0; r < 4; ++r) {
      f32x4 mv;
#pragma unroll
      for (int n = 0; n < 4; ++n) {
        const float af = aF[n][r];
        const float as = aS[n][r];
        const float sg = __builtin_amdgcn_rcpf(1.0f + __expf(-af));
        const float sp = fmaxf(as, 0.0f) + __logf(1.0f + __expf(-fabsf(as)));
        mv[n] = sg * sp;
      }
      *(f32x4*)&mlds[wv][quad * 4 + r][col * 4] = mv;
    }
    __builtin_amdgcn_wave_barrier();

    // segmented reduce over the 16 CSR positions (dst-sorted)
    float sum = 0.0f;
    int dcur = dsts[base];
#pragma unroll
    for (int p = 0; p < 16; ++p) {
      sum += mlds[wv][p][lane];
      const int dnxt = (p < 15) ? dsts[base + p + 1] : -1;
      if (dnxt != dcur) {
        atomicAdd(&aggr[(size_t)dcur * D1 + lane], sum * invc[dcur]);
        sum = 0.0f;
        dcur = dnxt;
      }
    }
    __builtin_amdgcn_wave_barrier();
  }
}

// ---------------- BN stats over meaned aggr ----------------
extern "C" __global__ void __launch_bounds__(256)
k_stats(const float* __restrict__ aggr, float* __restrict__ musum,
        float* __restrict__ sqsum) {
  const int j = threadIdx.x & 63;
  const int rid = (blockIdx.x * blockDim.x + threadIdx.x) >> 6;
  const int rstr = (gridDim.x * blockDim.x) >> 6;
  float s = 0.0f, sq = 0.0f;
  for (int i = rid; i < N_NODES; i += rstr) {
    const float v = aggr[(size_t)i * D1 + j];
    s += v;
    sq = fmaf(v, v, sq);
  }
  __shared__ float ls[256], lq[256];
  ls[threadIdx.x] = s;
  lq[threadIdx.x] = sq;
  __syncthreads();
  if (threadIdx.x < 64) {
    s = ls[j] + ls[64 + j] + ls[128 + j] + ls[192 + j];
    sq = lq[j] + lq[64 + j] + lq[128 + j] + lq[192 + j];
    atomicAdd(&musum[j], s);
    atomicAdd(&sqsum[j], sq);
  }
}

// ---------------- h = relu(h + bn(aggr)) with inline BN finalize ------------
extern "C" __global__ void __launch_bounds__(256)
k_update(float* __restrict__ h, const float* __restrict__ aggr,
         const float* __restrict__ musum, const float* __restrict__ sqsum,
         const float* __restrict__ gamma, const float* __restrict__ beta) {
  const size_t idx = (size_t)blockIdx.x * blockDim.x + threadIdx.x;
  if (idx >= (size_t)N_NODES * D1) return;
  const int j = (int)(idx & 63);
  const float mu = musum[j] * (1.0f / N_NODES);
  const float var = sqsum[j] * (1.0f / N_NODES) - mu * mu;
  const float r = gamma[j] * rsqrtf(var + BN_EPS);
  const float sh = beta[j] - mu * r;
  h[idx] = fmaxf(h[idx] + fmaf(aggr[idx], r, sh), 0.0f);
}

// ---------------- global mean pool (atomic) ----------------
extern "C" __global__ void __launch_bounds__(256)
k_pool(const float* __restrict__ h, const int* __restrict__ batch,
       float* __restrict__ pooled, float* __restrict__ gcnt) {
  const int lane = threadIdx.x & 63;
  const int wave = (blockIdx.x * blockDim.x + threadIdx.x) >> 6;
  const int nw = (gridDim.x * blockDim.x) >> 6;
  for (int i = wave; i < N_NODES; i += nw) {
    const int b = batch[i];
    atomicAdd(&pooled[(size_t)b * D1 + lane], h[(size_t)i * D1 + lane]);
    if (lane == 0) atomicAdd(&gcnt[b], 1.0f);
  }
}

// ---------------- final MLP chain, one wave per graph ----------------
extern "C" __global__ void __launch_bounds__(64)
k_mlp(const float* __restrict__ pooled, const float* __restrict__ gcnt,
      const float* __restrict__ lin1_w, const float* __restrict__ lin1_b,
      const float* __restrict__ fc_w, const float* __restrict__ fc_b,
      const float* __restrict__ lin2_w, const float* __restrict__ lin2_b,
      float* __restrict__ out) {
  const int g = blockIdx.x;
  const int j = threadIdx.x;
  __shared__ float vin[D1];
  const float inv = 1.0f / fmaxf(gcnt[g], 1.0f);
  float v = pooled[(size_t)g * D1 + j] * inv;
  for (int layer = 0; layer < 3; ++layer) {
    vin[j] = v;
    __syncthreads();
    const float* W;
    const float* B;
    if (layer == 0) {
      W = lin1_w;
      B = lin1_b;
    } else {
      W = fc_w + (size_t)(layer - 1) * D1 * D1;
      B = fc_b + (size_t)(layer - 1) * D1;
    }
    float acc = B[j];
#pragma unroll 16
    for (int k = 0; k < D1; ++k) acc = fmaf(vin[k], W[k * D1 + j], acc);
    v = fmaxf(acc, 0.0f);
    __syncthreads();
  }
  float p = v * lin2_w[j];
#pragma unroll
  for (int off = 32; off > 0; off >>= 1) p += __shfl_down(p, off);
  if (j == 0) out[g] = p + lin2_b[0];
}

extern "C" void kernel_launch(void* const* d_in, const int* in_sizes, int n_in,
                              void* d_out, int out_size, void* d_ws, size_t ws_size,
                              hipStream_t stream) {
  const float* x        = (const float*)d_in[0];
  const float* ea       = (const float*)d_in[1];
  const float* lin0_w   = (const float*)d_in[2];
  const float* lin0_b   = (const float*)d_in[3];
  const float* conv_wf  = (const float*)d_in[4];
  const float* conv_bf  = (const float*)d_in[5];
  const float* conv_ws  = (const float*)d_in[6];
  const float* conv_bs  = (const float*)d_in[7];
  const float* bn_gamma = (const float*)d_in[8];
  const float* bn_beta  = (const float*)d_in[9];
  const float* lin1_w   = (const float*)d_in[10];
  const float* lin1_b   = (const float*)d_in[11];
  const float* fc_w     = (const float*)d_in[12];
  const float* fc_b     = (const float*)d_in[13];
  const float* lin2_w   = (const float*)d_in[14];
  const float* lin2_b   = (const float*)d_in[15];
  const int*   ei       = (const int*)d_in[16];
  const int*   batch    = (const int*)d_in[17];

  uintptr_t p = (uintptr_t)d_ws;
  auto alloc = [&](size_t bytes) {
    p = (p + 255) & ~(size_t)255;
    void* r = (void*)p;
    p += bytes;
    return r;
  };
  float* h      = (float*)alloc((size_t)N_NODES * 64 * 4);
  float* pf     = (float*)alloc((size_t)N_NODES * 128 * 4);
  float* ps     = (float*)alloc((size_t)N_NODES * 128 * 4);
  float* aggr   = (float*)alloc((size_t)N_NODES * 64 * 4);
  float* musum  = (float*)alloc(128 * 4);  // musum[64] + sqsum[64] contiguous
  float* sqsum  = musum + 64;
  float* pooled = (float*)alloc((size_t)(NG * 64 + NG) * 4);  // + gcnt
  float* gcnt   = pooled + NG * 64;
  float* invc   = (float*)alloc((size_t)N_NODES * 4);
  int*   cnt    = (int*)alloc((size_t)N_NODES * 4);
  int*   rp     = (int*)alloc((size_t)(N_NODES + 1) * 4);
  int*   wptr   = (int*)alloc((size_t)N_NODES * 4);
  int*   srcs   = (int*)alloc((size_t)N_EDGES * 4);
  int*   dsts   = (int*)alloc((size_t)N_EDGES * 4);
  int*   eidx   = (int*)alloc((size_t)N_EDGES * 4);
  unsigned short* eapb = (unsigned short*)alloc((size_t)N_EDGES * 64 * 2);
  unsigned short* Bp   = (unsigned short*)alloc((size_t)NL * 16 * 64 * 8 * 2);

  hipMemsetAsync(cnt, 0, N_NODES * sizeof(int), stream);
  hipMemsetAsync(pooled, 0, (NG * 64 + NG) * sizeof(float), stream);

  k_lin0<<<256, 256, 0, stream>>>(x, lin0_w, lin0_b, h);
  k_cnt<<<(N_EDGES + 255) / 256, 256, 0, stream>>>(ei, cnt);
  k_scan<<<1, 1024, 0, stream>>>(cnt, rp, wptr);
  k_scatter<<<(N_EDGES + 255) / 256, 256, 0, stream>>>(ei, wptr, srcs, dsts, eidx);
  k_inv<<<(N_NODES + 255) / 256, 256, 0, stream>>>(rp, invc);
  k_eapack<<<(int)(((size_t)N_EDGES * 64 + 255) / 256), 256, 0, stream>>>(ea, eapb);
  k_wprep<<<(NL * 16 * 64 * 8 + 255) / 256, 256, 0, stream>>>(conv_wf, conv_ws, Bp);

  for (int l = 0; l < NL; ++l) {
    const float* wfl = conv_wf + (size_t)l * ZD * D1;
    const float* wsl = conv_ws + (size_t)l * ZD * D1;
    k_nodeproj<<<512, 256, 0, stream>>>(h, wfl, wsl, pf, ps);
    hipMemsetAsync(aggr, 0, (size_t)N_NODES * 64 * sizeof(float), stream);
    hipMemsetAsync(musum, 0, 128 * sizeof(float), stream);
    k_edgemm<<<EDGE_BLOCKS, 256, 0, stream>>>(
        pf, ps, eapb, srcs, dsts, eidx, invc, Bp + (size_t)l * 16 * 64 * 8,
        conv_bf + (size_t)l * D1, conv_bs + (size_t)l * D1, aggr);
    k_stats<<<256, 256, 0, stream>>>(aggr, musum, sqsum);
    k_update<<<(N_NODES * D1 + 255) / 256, 256, 0, stream>>>(
        h, aggr, musum, sqsum, bn_gamma + (size_t)l * D1, bn_beta + (size_t)l * D1);
  }

  k_pool<<<128, 256, 0, stream>>>(h, batch, pooled, gcnt);
  k_mlp<<<NG, 64, 0, stream>>>(pooled, gcnt, lin1_w, lin1_b, fc_w, fc_b,
                               lin2_w, lin2_b, (float*)d_out);
}

// Round 5
// 867.677 us; speedup vs baseline: 1.5591x; 1.1156x over previous
//
#include <hip/hip_runtime.h>
#include <hip/hip_bf16.h>

#define N_NODES 30000
#define N_EDGES 480000
#define NFEAT 92
#define EFEAT 50
#define D1 64
#define ZD 178
#define NL 3
#define NG 256
#define BN_EPS 1e-5f
#define NTILES (N_EDGES / 16)   // 30000
#define EDGE_BLOCKS 1875        // 7500 waves x 4 tiles = 30000 exactly

typedef __attribute__((ext_vector_type(8))) short bf16x8;
typedef __attribute__((ext_vector_type(4))) float f32x4;

static __device__ __forceinline__ unsigned short f2bf(float v) {
  __hip_bfloat16 b = __float2bfloat16(v);
  return *(unsigned short*)&b;
}

// ---------------- lin0: h = relu(x @ W0 + b0); also zeros aggrA ----------------
extern "C" __global__ void __launch_bounds__(256)
k_lin0(const float* __restrict__ x, const float* __restrict__ w,
       const float* __restrict__ b, float* __restrict__ h,
       float* __restrict__ aggrA) {
  const int lane = threadIdx.x & 63;
  const int wave = (blockIdx.x * blockDim.x + threadIdx.x) >> 6;
  const int nw = (gridDim.x * blockDim.x) >> 6;
  float wreg[NFEAT];
#pragma unroll
  for (int k = 0; k < NFEAT; ++k) wreg[k] = w[k * D1 + lane];
  const float bj = b[lane];
  for (int i = wave; i < N_NODES; i += nw) {
    const float2* xr = (const float2*)(x + (size_t)i * NFEAT);
    float acc = bj;
#pragma unroll
    for (int k = 0; k < NFEAT / 2; ++k) {
      const float2 v = xr[k];
      acc = fmaf(v.x, wreg[2 * k], acc);
      acc = fmaf(v.y, wreg[2 * k + 1], acc);
    }
    h[(size_t)i * D1 + lane] = fmaxf(acc, 0.0f);
    aggrA[(size_t)i * D1 + lane] = 0.0f;
  }
}

// ---------------- CSR build ----------------
extern "C" __global__ void __launch_bounds__(256)
k_cnt(const int* __restrict__ ei, int* __restrict__ cnt) {
  const int e = blockIdx.x * blockDim.x + threadIdx.x;
  if (e < N_EDGES) atomicAdd(&cnt[ei[N_EDGES + e]], 1);
}

// single-block scan: rp (exclusive prefix), wptr copy, invc = 1/max(cnt,1)
extern "C" __global__ void __launch_bounds__(1024)
k_scan(const int* __restrict__ cnt, int* __restrict__ rp, int* __restrict__ wptr,
       float* __restrict__ invc) {
  const int t = threadIdx.x;
  const int CH = (N_NODES + 1023) / 1024;  // 30
  int vals[CH];
  int s = 0;
#pragma unroll
  for (int k = 0; k < CH; ++k) {
    const int idx = t * CH + k;
    const int c = (idx < N_NODES) ? cnt[idx] : 0;
    vals[k] = s;
    s += c;
  }
  __shared__ int bs[1024];
  bs[t] = s;
  __syncthreads();
  for (int off = 1; off < 1024; off <<= 1) {
    int v = 0;
    if (t >= off) v = bs[t - off];
    __syncthreads();
    if (t >= off) bs[t] += v;
    __syncthreads();
  }
  const int prefix = (t == 0) ? 0 : bs[t - 1];
#pragma unroll
  for (int k = 0; k < CH; ++k) {
    const int idx = t * CH + k;
    if (idx < N_NODES) {
      const int v = prefix + vals[k];
      rp[idx] = v;
      wptr[idx] = v;
      const int c = (k + 1 < CH) ? (vals[k + 1] - vals[k])
                                 : (s - vals[k]);
      invc[idx] = 1.0f / fmaxf((float)c, 1.0f);
    }
  }
  if (t == 1023) rp[N_NODES] = bs[1023];
}

extern "C" __global__ void __launch_bounds__(256)
k_scatter(const int* __restrict__ ei, int* __restrict__ wptr,
          int* __restrict__ srcs, int* __restrict__ dsts,
          int* __restrict__ eidx) {
  const int e = blockIdx.x * blockDim.x + threadIdx.x;
  if (e < N_EDGES) {
    const int d = ei[N_EDGES + e];
    const int pos = atomicAdd(&wptr[d], 1);
    srcs[pos] = ei[e];
    dsts[pos] = d;
    eidx[pos] = e;
  }
}

// ---------------- graph boundaries from sorted batch ----------------
extern "C" __global__ void __launch_bounds__(256)
k_gb(const int* __restrict__ batch, int* __restrict__ grp) {
  const int i = blockIdx.x * blockDim.x + threadIdx.x;
  if (i >= N_NODES) return;
  const int b = batch[i];
  if (i == 0)
    for (int g = 0; g <= b; ++g) grp[g] = 0;
  else {
    const int pb = batch[i - 1];
    for (int g = pb + 1; g <= b; ++g) grp[g] = i;
  }
  if (i == N_NODES - 1)
    for (int g = b + 1; g <= NG; ++g) grp[g] = N_NODES;
}

// ---------------- pack edge_attr -> bf16 in CSR order, K padded to 64 -------
// half-wave per CSR position: coalesced 128B writes.
extern "C" __global__ void __launch_bounds__(256)
k_eapack(const float* __restrict__ ea, const int* __restrict__ eidx,
         unsigned short* __restrict__ eapb) {
  const int hw = (blockIdx.x * blockDim.x + threadIdx.x) >> 5;
  const int l2 = threadIdx.x & 31;
  const int nhw = (gridDim.x * blockDim.x) >> 5;
  for (int p = hw; p < N_EDGES; p += nhw) {
    const int e = eidx[p];
    unsigned int out = 0;
    if (l2 < 25) {
      const float2 v = *(const float2*)(ea + (size_t)e * EFEAT + l2 * 2);
      out = (unsigned int)f2bf(v.x) | ((unsigned int)f2bf(v.y) << 16);
    }
    *(unsigned int*)(eapb + ((size_t)p << 6) + l2 * 2) = out;
  }
}

// ---------------- prep B fragments (bf16) for all layers --------------------
extern "C" __global__ void __launch_bounds__(256)
k_wprep(const float* __restrict__ conv_wf, const float* __restrict__ conv_ws,
        unsigned short* __restrict__ Bp) {
  const int idx = blockIdx.x * blockDim.x + threadIdx.x;
  const int total = NL * 16 * 64 * 8;
  if (idx >= total) return;
  const int j = idx & 7;
  const int lane = (idx >> 3) & 63;
  const int frag = (idx >> 9) & 15;   // (m*2+t)*4+n
  const int l = idx >> 13;
  const int n = frag & 3;
  const int t = (frag >> 2) & 1;
  const int m = frag >> 3;
  const int k = t * 32 + (lane >> 4) * 8 + j;
  const int feat = (lane & 15) * 4 + n;
  float v = 0.0f;
  if (k < EFEAT) {
    const float* W = (m == 0) ? conv_wf : conv_ws;
    v = W[(size_t)l * ZD * D1 + (size_t)(128 + k) * D1 + feat];
  }
  Bp[idx] = f2bf(v);
}

// ---------------- node projections with fused BN-residual-ReLU update -------
// do_bn: hnew = relu(hin + bn(aggr)); wave0 stores hnew -> hout (ping-pong).
extern "C" __global__ void __launch_bounds__(256)
k_nodeproj(const float* __restrict__ hin, float* __restrict__ hout,
           const float* __restrict__ wfp, const float* __restrict__ wsm,
           float* __restrict__ pf, float* __restrict__ ps,
           const float* __restrict__ aggr, const float* __restrict__ musum,
           const float* __restrict__ sqsum, const float* __restrict__ gamma,
           const float* __restrict__ beta, int do_bn) {
  const int lane = threadIdx.x & 63;
  const int w = threadIdx.x >> 6;  // 0..3
  const float* W = (w < 2) ? wfp : wsm;
  const int roff = (w & 1) * 64;
  float wreg[D1];
#pragma unroll
  for (int k = 0; k < D1; ++k) wreg[k] = W[(size_t)(roff + k) * D1 + lane];
  float* out = (w < 2) ? pf : ps;
  const int ooff = (w & 1) * 64;
  float r = 0.0f, sh = 0.0f;
  if (do_bn) {
    const float mu = musum[lane] * (1.0f / N_NODES);
    const float var = sqsum[lane] * (1.0f / N_NODES) - mu * mu;
    r = gamma[lane] * rsqrtf(var + BN_EPS);
    sh = beta[lane] - mu * r;
  }
  __shared__ float hl[4][64];
  for (int i = blockIdx.x; i < N_NODES; i += gridDim.x) {
    float hv = hin[(size_t)i * D1 + lane];
    if (do_bn) {
      hv = fmaxf(hv + fmaf(aggr[(size_t)i * D1 + lane], r, sh), 0.0f);
      if (w == 0) hout[(size_t)i * D1 + lane] = hv;
    }
    hl[w][lane] = hv;
    __builtin_amdgcn_wave_barrier();
    const float4* hr = (const float4*)&hl[w][0];
    float acc = 0.0f;
#pragma unroll
    for (int k4 = 0; k4 < D1 / 4; ++k4) {
      const float4 v = hr[k4];
      acc = fmaf(v.x, wreg[4 * k4 + 0], acc);
      acc = fmaf(v.y, wreg[4 * k4 + 1], acc);
      acc = fmaf(v.z, wreg[4 * k4 + 2], acc);
      acc = fmaf(v.w, wreg[4 * k4 + 3], acc);
    }
    out[(size_t)i * 128 + ooff + lane] = acc;
    __builtin_amdgcn_wave_barrier();
  }
}

// ---------------- MFMA edge kernel (CSR-ordered A, coalesced) ---------------
extern "C" __global__ void __launch_bounds__(256, 2)
k_edgemm(const float* __restrict__ pf, const float* __restrict__ ps,
         const unsigned short* __restrict__ eapb,
         const int* __restrict__ srcs, const int* __restrict__ dsts,
         const float* __restrict__ invc,
         const unsigned short* __restrict__ Bp,
         const float* __restrict__ bfp, const float* __restrict__ bsp,
         float* __restrict__ aggr, float* __restrict__ musum,
         float* __restrict__ sqsum) {
  const int lane = threadIdx.x & 63;
  const int wv = threadIdx.x >> 6;
  const int col = lane & 15;
  const int quad = lane >> 4;
  __shared__ float mlds[4][16][68];

  if (blockIdx.x == 0 && wv == 0) {  // zero stats accumulators for k_stats
    musum[lane] = 0.0f;
    sqsum[lane] = 0.0f;
  }

  bf16x8 Bf[2][2][4];
#pragma unroll
  for (int m = 0; m < 2; ++m)
#pragma unroll
    for (int t = 0; t < 2; ++t)
#pragma unroll
      for (int n = 0; n < 4; ++n)
        Bf[m][t][n] = *(const bf16x8*)(Bp + ((((m * 2 + t) * 4 + n) * 64 + lane) * 8));

  const f32x4 bf4 = *(const f32x4*)(bfp + col * 4);
  const f32x4 bs4 = *(const f32x4*)(bsp + col * 4);

  const int wave0 = blockIdx.x * 4 + wv;
  for (int t = wave0; t < NTILES; t += EDGE_BLOCKS * 4) {
    const int base = t * 16;
    // indices: int4 vector loads (16B aligned: base%16==0, quad*4%4==0)
    const int4 d4 = *(const int4*)(dsts + base + quad * 4);
    const int4 s4 = *(const int4*)(srcs + base + quad * 4);
    const int* dr = (const int*)&d4;
    const int* sr = (const int*)&s4;
    // A fragments: CSR-ordered eapb -> contiguous 2KB per tile, coalesced
    const bf16x8 Af0 = *(const bf16x8*)(eapb + ((size_t)(base + col) << 6) + quad * 8);
    const bf16x8 Af1 = *(const bf16x8*)(eapb + ((size_t)(base + col) << 6) + 32 + quad * 8);

    // C init: fp32 node projections + bias
    f32x4 aF[4], aS[4];
#pragma unroll
    for (int r = 0; r < 4; ++r) {
      const int d = dr[r];
      const int s = sr[r];
      const f32x4 pfd = *(const f32x4*)(pf + (size_t)d * 128 + col * 4);
      const f32x4 pfs = *(const f32x4*)(pf + (size_t)s * 128 + 64 + col * 4);
      const f32x4 psd = *(const f32x4*)(ps + (size_t)d * 128 + col * 4);
      const f32x4 pss = *(const f32x4*)(ps + (size_t)s * 128 + 64 + col * 4);
#pragma unroll
      for (int n = 0; n < 4; ++n) {
        aF[n][r] = pfd[n] + pfs[n] + bf4[n];
        aS[n][r] = psd[n] + pss[n] + bs4[n];
      }
    }

#pragma unroll
    for (int n = 0; n < 4; ++n) {
      aF[n] = __builtin_amdgcn_mfma_f32_16x16x32_bf16(Af0, Bf[0][0][n], aF[n], 0, 0, 0);
      aF[n] = __builtin_amdgcn_mfma_f32_16x16x32_bf16(Af1, Bf[0][1][n], aF[n], 0, 0, 0);
      aS[n] = __builtin_amdgcn_mfma_f32_16x16x32_bf16(Af0, Bf[1][0][n], aS[n], 0, 0, 0);
      aS[n] = __builtin_amdgcn_mfma_f32_16x16x32_bf16(Af1, Bf[1][1][n], aS[n], 0, 0, 0);
    }

    // epilogue: m = sigmoid(af) * softplus(as) -> LDS tile
#pragma unroll
    for (int r = 0; r < 4; ++r) {
      f32x4 mv;
#pragma unroll
      for (int n = 0; n < 4; ++n) {
        const float af = aF[n][r];
        const float as = aS[n][r];
        const float sg = __builtin_amdgcn_rcpf(1.0f + __expf(-af));
        const float sp = fmaxf(as, 0.0f) + __logf(1.0f + __expf(-fabsf(as)));
        mv[n] = sg * sp;
      }
      *(f32x4*)&mlds[wv][quad * 4 + r][col * 4] = mv;
    }
    __builtin_amdgcn_wave_barrier();

    // segmented reduce over the 16 dst-sorted CSR rows
    float sum = 0.0f;
    int dcur = dr[0] /* == dsts[base] only if quad==0 */;
    dcur = dsts[base];
#pragma unroll
    for (int p = 0; p < 16; ++p) {
      sum += mlds[wv][p][lane];
      const int dnxt = (p < 15) ? dsts[base + p + 1] : -1;
      if (dnxt != dcur) {
        atomicAdd(&aggr[(size_t)dcur * D1 + lane], sum * invc[dcur]);
        sum = 0.0f;
        dcur = dnxt;
      }
    }
    __builtin_amdgcn_wave_barrier();
  }
}

// ---------------- BN stats over meaned aggr; optionally zero other buffer ---
extern "C" __global__ void __launch_bounds__(256)
k_stats(const float* __restrict__ aggr, float* __restrict__ musum,
        float* __restrict__ sqsum, float* __restrict__ zbuf) {
  const int j = threadIdx.x & 63;
  const int rid = (blockIdx.x * blockDim.x + threadIdx.x) >> 6;
  const int rstr = (gridDim.x * blockDim.x) >> 6;
  float s = 0.0f, sq = 0.0f;
  for (int i = rid; i < N_NODES; i += rstr) {
    const float v = aggr[(size_t)i * D1 + j];
    s += v;
    sq = fmaf(v, v, sq);
    if (zbuf) zbuf[(size_t)i * D1 + j] = 0.0f;
  }
  __shared__ float ls[256], lq[256];
  ls[threadIdx.x] = s;
  lq[threadIdx.x] = sq;
  __syncthreads();
  if (threadIdx.x < 64) {
    s = ls[j] + ls[64 + j] + ls[128 + j] + ls[192 + j];
    sq = lq[j] + lq[64 + j] + lq[128 + j] + lq[192 + j];
    atomicAdd(&musum[j], s);
    atomicAdd(&sqsum[j], sq);
  }
}

// ---------------- segmented pool with fused final BN update -----------------
// one block (4 waves) per graph; nodes contiguous (batch sorted); no atomics.
extern "C" __global__ void __launch_bounds__(256)
k_pool(const float* __restrict__ h, const float* __restrict__ aggr,
       const float* __restrict__ musum, const float* __restrict__ sqsum,
       const float* __restrict__ gamma, const float* __restrict__ beta,
       const int* __restrict__ grp, float* __restrict__ pooled) {
  const int g = blockIdx.x;
  const int lane = threadIdx.x & 63;
  const int wv = threadIdx.x >> 6;
  const float mu = musum[lane] * (1.0f / N_NODES);
  const float var = sqsum[lane] * (1.0f / N_NODES) - mu * mu;
  const float r = gamma[lane] * rsqrtf(var + BN_EPS);
  const float sh = beta[lane] - mu * r;
  const int s = grp[g], e = grp[g + 1];
  float acc = 0.0f;
  for (int i = s + wv; i < e; i += 4) {
    const float hv = h[(size_t)i * D1 + lane];
    const float av = aggr[(size_t)i * D1 + lane];
    acc += fmaxf(hv + fmaf(av, r, sh), 0.0f);
  }
  __shared__ float red[4][64];
  red[wv][lane] = acc;
  __syncthreads();
  if (threadIdx.x < 64)
    pooled[(size_t)g * D1 + threadIdx.x] =
        red[0][threadIdx.x] + red[1][threadIdx.x] + red[2][threadIdx.x] + red[3][threadIdx.x];
}

// ---------------- final MLP chain, one wave per graph ----------------
extern "C" __global__ void __launch_bounds__(64)
k_mlp(const float* __restrict__ pooled, const int* __restrict__ grp,
      const float* __restrict__ lin1_w, const float* __restrict__ lin1_b,
      const float* __restrict__ fc_w, const float* __restrict__ fc_b,
      const float* __restrict__ lin2_w, const float* __restrict__ lin2_b,
      float* __restrict__ out) {
  const int g = blockIdx.x;
  const int j = threadIdx.x;
  __shared__ float vin[D1];
  const float inv = 1.0f / fmaxf((float)(grp[g + 1] - grp[g]), 1.0f);
  float v = pooled[(size_t)g * D1 + j] * inv;
  for (int layer = 0; layer < 3; ++layer) {
    vin[j] = v;
    __syncthreads();
    const float* W;
    const float* B;
    if (layer == 0) {
      W = lin1_w;
      B = lin1_b;
    } else {
      W = fc_w + (size_t)(layer - 1) * D1 * D1;
      B = fc_b + (size_t)(layer - 1) * D1;
    }
    float acc = B[j];
#pragma unroll 16
    for (int k = 0; k < D1; ++k) acc = fmaf(vin[k], W[k * D1 + j], acc);
    v = fmaxf(acc, 0.0f);
    __syncthreads();
  }
  float p = v * lin2_w[j];
#pragma unroll
  for (int off = 32; off > 0; off >>= 1) p += __shfl_down(p, off);
  if (j == 0) out[g] = p + lin2_b[0];
}

extern "C" void kernel_launch(void* const* d_in, const int* in_sizes, int n_in,
                              void* d_out, int out_size, void* d_ws, size_t ws_size,
                              hipStream_t stream) {
  const float* x        = (const float*)d_in[0];
  const float* ea       = (const float*)d_in[1];
  const float* lin0_w   = (const float*)d_in[2];
  const float* lin0_b   = (const float*)d_in[3];
  const float* conv_wf  = (const float*)d_in[4];
  const float* conv_bf  = (const float*)d_in[5];
  const float* conv_ws  = (const float*)d_in[6];
  const float* conv_bs  = (const float*)d_in[7];
  const float* bn_gamma = (const float*)d_in[8];
  const float* bn_beta  = (const float*)d_in[9];
  const float* lin1_w   = (const float*)d_in[10];
  const float* lin1_b   = (const float*)d_in[11];
  const float* fc_w     = (const float*)d_in[12];
  const float* fc_b     = (const float*)d_in[13];
  const float* lin2_w   = (const float*)d_in[14];
  const float* lin2_b   = (const float*)d_in[15];
  const int*   ei       = (const int*)d_in[16];
  const int*   batch    = (const int*)d_in[17];

  uintptr_t p = (uintptr_t)d_ws;
  auto alloc = [&](size_t bytes) {
    p = (p + 255) & ~(size_t)255;
    void* r = (void*)p;
    p += bytes;
    return r;
  };
  float* h0     = (float*)alloc((size_t)N_NODES * 64 * 4);
  float* h1     = (float*)alloc((size_t)N_NODES * 64 * 4);
  float* pf     = (float*)alloc((size_t)N_NODES * 128 * 4);
  float* ps     = (float*)alloc((size_t)N_NODES * 128 * 4);
  float* aggrA  = (float*)alloc((size_t)N_NODES * 64 * 4);
  float* aggrB  = (float*)alloc((size_t)N_NODES * 64 * 4);
  float* musum  = (float*)alloc(128 * 4);
  float* sqsum  = musum + 64;
  float* pooled = (float*)alloc((size_t)NG * 64 * 4);
  float* invc   = (float*)alloc((size_t)N_NODES * 4);
  int*   cnt    = (int*)alloc((size_t)N_NODES * 4);
  int*   rp     = (int*)alloc((size_t)(N_NODES + 1) * 4);
  int*   wptr   = (int*)alloc((size_t)N_NODES * 4);
  int*   srcs   = (int*)alloc((size_t)N_EDGES * 4);
  int*   dsts   = (int*)alloc((size_t)N_EDGES * 4);
  int*   eidx   = (int*)alloc((size_t)N_EDGES * 4);
  int*   grp    = (int*)alloc((size_t)(NG + 1) * 4);
  unsigned short* eapb = (unsigned short*)alloc((size_t)N_EDGES * 64 * 2);
  unsigned short* Bp   = (unsigned short*)alloc((size_t)NL * 16 * 64 * 8 * 2);

  hipMemsetAsync(cnt, 0, N_NODES * sizeof(int), stream);

  k_lin0<<<512, 256, 0, stream>>>(x, lin0_w, lin0_b, h0, aggrA);
  k_cnt<<<(N_EDGES + 255) / 256, 256, 0, stream>>>(ei, cnt);
  k_scan<<<1, 1024, 0, stream>>>(cnt, rp, wptr, invc);
  k_scatter<<<(N_EDGES + 255) / 256, 256, 0, stream>>>(ei, wptr, srcs, dsts, eidx);
  k_gb<<<(N_NODES + 255) / 256, 256, 0, stream>>>(batch, grp);
  k_eapack<<<4096, 256, 0, stream>>>(ea, eidx, eapb);
  k_wprep<<<(NL * 16 * 64 * 8 + 255) / 256, 256, 0, stream>>>(conv_wf, conv_ws, Bp);

  float* aggr_of[NL] = {aggrA, aggrB, aggrA};
  float* zb_of[NL]   = {aggrB, aggrA, nullptr};
  const float* hin_of[NL]  = {h0, h0, h1};
  float* hout_of[NL]       = {h0, h1, h0};

  for (int l = 0; l < NL; ++l) {
    const float* wfl = conv_wf + (size_t)l * ZD * D1;
    const float* wsl = conv_ws + (size_t)l * ZD * D1;
    // fused: update h with layer (l-1) BN, then project
    k_nodeproj<<<512, 256, 0, stream>>>(
        hin_of[l], hout_of[l], wfl, wsl, pf, ps,
        (l == 0) ? nullptr : aggr_of[l - 1], musum, sqsum,
        bn_gamma + (size_t)(l - 1) * D1, bn_beta + (size_t)(l - 1) * D1, l != 0);
    k_edgemm<<<EDGE_BLOCKS, 256, 0, stream>>>(
        pf, ps, eapb, srcs, dsts, invc, Bp + (size_t)l * 16 * 64 * 8,
        conv_bf + (size_t)l * D1, conv_bs + (size_t)l * D1,
        aggr_of[l], musum, sqsum);
    k_stats<<<256, 256, 0, stream>>>(aggr_of[l], musum, sqsum, zb_of[l]);
  }

  k_pool<<<NG, 256, 0, stream>>>(h0, aggr_of[2], musum, sqsum,
                                 bn_gamma + (size_t)2 * D1, bn_beta + (size_t)2 * D1,
                                 grp, pooled);
  k_mlp<<<NG, 64, 0, stream>>>(pooled, grp, lin1_w, lin1_b, fc_w, fc_b,
                               lin2_w, lin2_b, (float*)d_out);
}